// Round 4
// baseline (364.094 us; speedup 1.0000x reference)
//
#include <hip/hip_runtime.h>

#define MM 4096
#define NN 4096
#define KK 4096
#define BM 128
#define BN 128
#define BK 64
#define NT (KK / BK)

typedef __attribute__((ext_vector_type(8))) _Float16 f16x8;
typedef __attribute__((ext_vector_type(2))) _Float16 f16x2;
typedef __attribute__((ext_vector_type(4))) float f32x4;

__device__ __forceinline__ f16x2 pk16(float a, float b) {
  return __builtin_bit_cast(f16x2, __builtin_amdgcn_cvt_pkrtz(a, b));
}

__global__ __launch_bounds__(256, 2) void wq_gemm(
    const float* __restrict__ A, const int* __restrict__ Q,
    const float* __restrict__ S, const float* __restrict__ Z,
    float* __restrict__ C) {
  // Linear LDS tiles: byte(row,k) = row*128 + 2k
  __shared__ __align__(16) _Float16 AsBuf[2][BM * BK];  // [m][k]
  __shared__ __align__(16) _Float16 BsBuf[2][BN * BK];  // [n][k] (B^T tile)

  const int tid = threadIdx.x;
  const int lane = tid & 63;
  const int wid = tid >> 6;

  // bijective XCD swizzle (nwg=1024 % 8 == 0); m fast-varying
  const int nwg = (int)gridDim.x;
  const int bid0 = (int)blockIdx.x;
  const int wg = (bid0 & 7) * (nwg >> 3) + (bid0 >> 3);
  const int m0 = (wg & 31) * BM;
  const int n0 = (wg >> 5) * BN;

  // ---- A staging (fp32 -> fp16): thread owns rows {a_m,+32,+64,+96} x 8 k
  const int a_m = tid >> 3;
  const int a_k = (tid & 7) * 8;
  const float* a_src = A + (size_t)(m0 + a_m) * KK + a_k;
  const int a_woff = a_m * (BK * 2) + a_k * 2;  // LDS byte offset

  // ---- B staging: thread owns one n column, 32 consecutive k
  const int n_loc = tid & 127;
  const int kk0 = (tid >> 7) * 32;
  const int* q_src = Q + (size_t)kk0 * NN + (n0 + n_loc);
  const float* s_src = S + (n0 + n_loc);
  const float* z_src = Z + (n0 + n_loc);
  int bw_off[4];
#pragma unroll
  for (int j = 0; j < 4; ++j)
    bw_off[j] = n_loc * (BK * 2) + (kk0 + j * 8) * 2;

  // ---- compute-side fragment addressing
  const int wm = wid >> 1, wn = wid & 1;
  const int lr = lane & 15, lg = lane >> 4;
  int a_row[4], b_row[4], koff[2];
#pragma unroll
  for (int f = 0; f < 4; ++f) {
    a_row[f] = (wm * 64 + f * 16 + lr) * (BK * 2);
    b_row[f] = (wn * 64 + f * 16 + lr) * (BK * 2);
  }
#pragma unroll
  for (int ks = 0; ks < 2; ++ks)
    koff[ks] = (ks * 32 + lg * 8) * 2;

  f32x4 acc[4][4];
#pragma unroll
  for (int i = 0; i < 4; ++i)
#pragma unroll
    for (int j = 0; j < 4; ++j) acc[i][j] = (f32x4){0.f, 0.f, 0.f, 0.f};

  f32x4 av[8];
  int qv[32];
  float sf, bf;

  // ---- staging helpers (register loads, then LDS writes)
  auto stage_load = [&](int t) {
    const float* ap = a_src + (size_t)t * BK;
#pragma unroll
    for (int p = 0; p < 4; ++p) {
      av[p * 2] = *(const f32x4*)(ap + (size_t)p * 32 * KK);
      av[p * 2 + 1] = *(const f32x4*)(ap + (size_t)p * 32 * KK + 4);
    }
    const int* qp = q_src + (size_t)t * BK * NN;
#pragma unroll
    for (int i = 0; i < 32; ++i) qv[i] = qp[(size_t)i * NN];
    const int g = t >> 1;  // group constant across the 64-k tile (GS=128)
    sf = s_src[(size_t)g * NN];
    bf = -z_src[(size_t)g * NN] * sf;
  };

  auto stage_write = [&](int c) {
    // A: fp32 -> fp16 (exact: values round-trip fp16)
    char* as = (char*)&AsBuf[c][0];
#pragma unroll
    for (int p = 0; p < 4; ++p) {
      union { f16x2 h2[4]; f16x8 v; } u;
      f32x4 v0 = av[p * 2], v1 = av[p * 2 + 1];
      u.h2[0] = pk16(v0[0], v0[1]);
      u.h2[1] = pk16(v0[2], v0[3]);
      u.h2[2] = pk16(v1[0], v1[1]);
      u.h2[3] = pk16(v1[2], v1[3]);
      *(f16x8*)(as + a_woff + p * 4096) = u.v;
    }
    // B: dequant int4-in-int32 -> fp16
    char* bs = (char*)&BsBuf[c][0];
#pragma unroll
    for (int j = 0; j < 4; ++j) {
      union { f16x2 h2[4]; f16x8 v; } u;
#pragma unroll
      for (int p = 0; p < 4; ++p) {
        float w0 = (float)qv[j * 8 + p * 2] * sf + bf;
        float w1 = (float)qv[j * 8 + p * 2 + 1] * sf + bf;
        u.h2[p] = pk16(w0, w1);
      }
      *(f16x8*)(bs + bw_off[j]) = u.v;
    }
  };

  // ================= prologue =================
  stage_load(0);
  stage_write(0);
  __syncthreads();

  // ================= main K loop =================
  for (int t = 0; t < NT; ++t) {
    const int c = t & 1;
    if (t + 1 < NT) stage_load(t + 1);  // global loads hide under MFMA

    {
      const char* as = (const char*)&AsBuf[c][0];
      const char* bs = (const char*)&BsBuf[c][0];
#pragma unroll
      for (int ks = 0; ks < 2; ++ks) {
        f16x8 af[4], bfr[4];
#pragma unroll
        for (int f = 0; f < 4; ++f) {
          af[f] = *(const f16x8*)(as + (a_row[f] + koff[ks]));
          bfr[f] = *(const f16x8*)(bs + (b_row[f] + koff[ks]));
        }
#pragma unroll
        for (int i = 0; i < 4; ++i)
#pragma unroll
          for (int j = 0; j < 4; ++j)
            acc[i][j] = __builtin_amdgcn_mfma_f32_16x16x32_f16(
                af[i], bfr[j], acc[i][j], 0, 0, 0);
      }
    }

    if (t + 1 < NT) stage_write(c ^ 1);
    __syncthreads();
  }

  // ================= epilogue: C/D col=lane&15, row=(lane>>4)*4+reg =================
#pragma unroll
  for (int i = 0; i < 4; ++i) {
    const int row0 = m0 + wm * 64 + i * 16 + lg * 4;
#pragma unroll
    for (int j = 0; j < 4; ++j) {
      const int col = n0 + wn * 64 + j * 16 + lr;
#pragma unroll
      for (int r = 0; r < 4; ++r)
        C[(size_t)(row0 + r) * NN + col] = acc[i][j][r];
    }
  }
}

extern "C" void kernel_launch(void* const* d_in, const int* in_sizes, int n_in,
                              void* d_out, int out_size, void* d_ws, size_t ws_size,
                              hipStream_t stream) {
  const float* A = (const float*)d_in[0];
  const int* Q = (const int*)d_in[1];
  const float* S = (const float*)d_in[2];
  const float* Z = (const float*)d_in[3];
  float* C = (float*)d_out;
  dim3 grid((MM / BM) * (NN / BN));
  dim3 block(256);
  wq_gemm<<<grid, block, 0, stream>>>(A, Q, S, Z, C);
}

// Round 5
// 322.435 us; speedup vs baseline: 1.1292x; 1.1292x over previous
//
#include <hip/hip_runtime.h>

#define MM 4096
#define NN 4096
#define KK 4096
#define BM 128
#define BN 128
#define BK 64
#define NT (KK / BK)

typedef __attribute__((ext_vector_type(8))) _Float16 f16x8;
typedef __attribute__((ext_vector_type(2))) _Float16 f16x2;
typedef __attribute__((ext_vector_type(4))) float f32x4;

__device__ __forceinline__ f16x2 pk16(float a, float b) {
  return __builtin_bit_cast(f16x2, __builtin_amdgcn_cvt_pkrtz(a, b));
}

__global__ __launch_bounds__(256, 2) void wq_gemm(
    const float* __restrict__ A, const int* __restrict__ Q,
    const float* __restrict__ S, const float* __restrict__ Z,
    float* __restrict__ C) {
  // XOR-swizzled LDS tiles: byte(row,kb) = row*128 + (kb ^ ((row&7)<<4))
  // (reg-staged writes AND reads use the same involution -> consistent)
  __shared__ __align__(16) _Float16 AsBuf[2][BM * BK];  // [m][k]
  __shared__ __align__(16) _Float16 BsBuf[2][BN * BK];  // [n][k] (B^T tile)

  const int tid = threadIdx.x;
  const int lane = tid & 63;
  const int wid = tid >> 6;

  // bijective XCD swizzle (nwg=1024 % 8 == 0); m fast-varying
  const int nwg = (int)gridDim.x;
  const int bid0 = (int)blockIdx.x;
  const int wg = (bid0 & 7) * (nwg >> 3) + (bid0 >> 3);
  const int m0 = (wg & 31) * BM;
  const int n0 = (wg >> 5) * BN;

  // ---- A staging (fp32 -> fp16): thread owns rows {a_m,+32,+64,+96} x 8 k
  const int a_m = tid >> 3;
  const int a_k = (tid & 7) * 8;
  const float* a_src = A + (size_t)(m0 + a_m) * KK + a_k;
  // swizzled LDS byte offset for this thread's 16B chunk
  const int a_woff = a_m * (BK * 2) + ((a_k * 2) ^ ((a_m & 7) << 4));

  // ---- B staging: thread owns one n column, 32 consecutive k
  const int n_loc = tid & 127;
  const int kk0 = (tid >> 7) * 32;
  const int* q_src = Q + (size_t)kk0 * NN + (n0 + n_loc);
  const float* s_src = S + (n0 + n_loc);
  const float* z_src = Z + (n0 + n_loc);
  int bw_off[4];
#pragma unroll
  for (int j = 0; j < 4; ++j)
    bw_off[j] = n_loc * (BK * 2) + (((kk0 + j * 8) * 2) ^ ((n_loc & 7) << 4));

  // ---- compute-side fragment addressing
  const int wm = wid >> 1, wn = wid & 1;
  const int lr = lane & 15, lg = lane >> 4;
  const int rx = (lr & 7) << 4;  // row-derived XOR term (row&7 == lr&7)
  int a_row[4], b_row[4], koffx[2];
#pragma unroll
  for (int f = 0; f < 4; ++f) {
    a_row[f] = (wm * 64 + f * 16 + lr) * (BK * 2);
    b_row[f] = (wn * 64 + f * 16 + lr) * (BK * 2);
  }
#pragma unroll
  for (int ks = 0; ks < 2; ++ks)
    koffx[ks] = ((ks * 32 + lg * 8) * 2) ^ rx;

  f32x4 acc[4][4];
#pragma unroll
  for (int i = 0; i < 4; ++i)
#pragma unroll
    for (int j = 0; j < 4; ++j) acc[i][j] = (f32x4){0.f, 0.f, 0.f, 0.f};

  f32x4 av[8];
  int qv[32];
  float sf, bf;

  // ---- staging helpers (register loads, then LDS writes)
  auto stage_load = [&](int t) {
    const float* ap = a_src + (size_t)t * BK;
#pragma unroll
    for (int p = 0; p < 4; ++p) {
      av[p * 2] = *(const f32x4*)(ap + (size_t)p * 32 * KK);
      av[p * 2 + 1] = *(const f32x4*)(ap + (size_t)p * 32 * KK + 4);
    }
    const int* qp = q_src + (size_t)t * BK * NN;
#pragma unroll
    for (int i = 0; i < 32; ++i) qv[i] = qp[(size_t)i * NN];
    const int g = t >> 1;  // group constant across the 64-k tile (GS=128)
    sf = s_src[(size_t)g * NN];
    bf = -z_src[(size_t)g * NN] * sf;
  };

  auto stage_write = [&](int c) {
    // A: fp32 -> fp16 (exact: values round-trip fp16)
    char* as = (char*)&AsBuf[c][0];
#pragma unroll
    for (int p = 0; p < 4; ++p) {
      union { f16x2 h2[4]; f16x8 v; } u;
      f32x4 v0 = av[p * 2], v1 = av[p * 2 + 1];
      u.h2[0] = pk16(v0[0], v0[1]);
      u.h2[1] = pk16(v0[2], v0[3]);
      u.h2[2] = pk16(v1[0], v1[1]);
      u.h2[3] = pk16(v1[2], v1[3]);
      *(f16x8*)(as + a_woff + p * 4096) = u.v;
    }
    // B: dequant int4-in-int32 -> fp16
    char* bs = (char*)&BsBuf[c][0];
#pragma unroll
    for (int j = 0; j < 4; ++j) {
      union { f16x2 h2[4]; f16x8 v; } u;
#pragma unroll
      for (int p = 0; p < 4; ++p) {
        float w0 = (float)qv[j * 8 + p * 2] * sf + bf;
        float w1 = (float)qv[j * 8 + p * 2 + 1] * sf + bf;
        u.h2[p] = pk16(w0, w1);
      }
      *(f16x8*)(bs + bw_off[j]) = u.v;
    }
  };

  // ================= prologue =================
  stage_load(0);
  stage_write(0);
  __syncthreads();

  // ================= main K loop =================
  for (int t = 0; t < NT; ++t) {
    const int c = t & 1;
    if (t + 1 < NT) stage_load(t + 1);  // global loads hide under MFMA

    {
      const char* as = (const char*)&AsBuf[c][0];
      const char* bs = (const char*)&BsBuf[c][0];
#pragma unroll
      for (int ks = 0; ks < 2; ++ks) {
        f16x8 af[4], bfr[4];
#pragma unroll
        for (int f = 0; f < 4; ++f) {
          // swizzled read: rows differ per lane, XOR folded into koffx
          af[f] = *(const f16x8*)(as + (a_row[f] + koffx[ks]));
          bfr[f] = *(const f16x8*)(bs + (b_row[f] + koffx[ks]));
        }
#pragma unroll
        for (int i = 0; i < 4; ++i)
#pragma unroll
          for (int j = 0; j < 4; ++j)
            acc[i][j] = __builtin_amdgcn_mfma_f32_16x16x32_f16(
                af[i], bfr[j], acc[i][j], 0, 0, 0);
      }
    }

    if (t + 1 < NT) stage_write(c ^ 1);
    __syncthreads();
  }

  // ================= epilogue: C/D col=lane&15, row=(lane>>4)*4+reg =================
#pragma unroll
  for (int i = 0; i < 4; ++i) {
    const int row0 = m0 + wm * 64 + i * 16 + lg * 4;
#pragma unroll
    for (int j = 0; j < 4; ++j) {
      const int col = n0 + wn * 64 + j * 16 + lr;
#pragma unroll
      for (int r = 0; r < 4; ++r)
        C[(size_t)(row0 + r) * NN + col] = acc[i][j][r];
    }
  }
}

extern "C" void kernel_launch(void* const* d_in, const int* in_sizes, int n_in,
                              void* d_out, int out_size, void* d_ws, size_t ws_size,
                              hipStream_t stream) {
  const float* A = (const float*)d_in[0];
  const int* Q = (const int*)d_in[1];
  const float* S = (const float*)d_in[2];
  const float* Z = (const float*)d_in[3];
  float* C = (float*)d_out;
  dim3 grid((MM / BM) * (NN / BN));
  dim3 block(256);
  wq_gemm<<<grid, block, 0, stream>>>(A, Q, S, Z, C);
}